// Round 1
// baseline (312.983 us; speedup 1.0000x reference)
//
#include <hip/hip_runtime.h>
#include <math.h>

#define KK      7
#define C1      21
#define NPLANES (KK * KK * C1)   // 1029
#define H       100
#define W       100
#define TS      101              // padded LDS row stride: bank stride 5 (coprime 32)
#define NCHUNK  ((H * W) / 4)    // 2500 float4 chunks per plane
#define PREFK   10               // ceil(2500 / 256)
#define SCHUNK  20               // register-scan chunk (100 = 5 * 20)

// ---------------------------------------------------------------------------
// Workspace-free pipeline:
//   zero_out      : out[n][c] = 0                       (168 KB, trivial)
//   plane_accum   : per plane-pair block, integral image in LDS, then
//                   atomicAdd(S / (49*area)) directly into out[n][c]
//   softmax_rows  : in-place softmax over the 21 channels of each ROI
// No d_ws usage at all -> tests the theory that the ~98us 659MB workspace
// re-poison fill sits inside the timed window only when ws is used.
// ---------------------------------------------------------------------------

__global__ __launch_bounds__(256) void zero_out(float* __restrict__ out, int n)
{
    int i = blockIdx.x * 256 + threadIdx.x;
    if (i < n) out[i] = 0.0f;
}

// ---------------------------------------------------------------------------
// Stage 1: one block per PAIR of planes (grid 515, 3 blocks/CU co-resident).
// Changes vs previous version:
//  - prefix scans are CHUNKED REGISTER scans: 20 independent ds_reads issue
//    back-to-back (pipelined, ~6cy each) instead of 100 serial in-order LDS
//    read->add->write round-trips (~100cy each). Bank patterns unchanged
//    (conflict-free per unrolled index).
//  - ROI phase atomicAdds the area-normalized contribution straight into
//    out[n][c]; no partial[] workspace, no reduce kernel.
// ---------------------------------------------------------------------------
__global__ __launch_bounds__(256) void plane_accum(
    const float* __restrict__ src,   // full cls_conv_out
    size_t batch_off,                // offset of last batch element (elements)
    const int*  __restrict__ rois,   // [nrois][4] = ymin,xmin,ymax,xmax
    int nrois,
    float* __restrict__ acc)         // == d_out, [nrois][C1]
{
    const int t  = threadIdx.x;
    const int p0 = blockIdx.x * 2;
    const int p1 = p0 + 1;
    const bool has_p1 = (p1 < NPLANES);

    __shared__ float tile[H * TS];   // 40400 B

    // ---- stage plane 0 (float4 global -> scalar padded LDS) ----
    {
        const float4* p4 = (const float4*)(src + batch_off + (size_t)p0 * (H * W));
        #pragma unroll
        for (int k = 0; k < PREFK; ++k) {
            int i = t + 256 * k;
            if (i < NCHUNK) {
                float4 v = p4[i];
                int g = i * 4;
                int y = g / W, x = g - y * W;        // rows don't split (100%4==0)
                float* d = &tile[y * TS + x];
                d[0] = v.x; d[1] = v.y; d[2] = v.z; d[3] = v.w;
            }
        }
    }
    __syncthreads();

    // ---- issue prefetch of plane 1 into registers (loads stay in flight) ----
    float4 pref[PREFK];
    if (has_p1) {
        const float4* p4 = (const float4*)(src + batch_off + (size_t)p1 * (H * W));
        #pragma unroll
        for (int k = 0; k < PREFK; ++k) {
            int i = t + 256 * k;
            if (i < NCHUNK) pref[k] = p4[i];
        }
    }

    for (int pass = 0; pass < 2; ++pass) {
        const int p = p0 + pass;
        if (p >= NPLANES) break;
        const int jl = p / C1;
        const int c  = p - jl * C1;
        const int l  = jl % KK;
        const int j  = jl / KK;

        if (pass == 1) {
            // overwrite tile with the prefetched plane
            __syncthreads();          // all pass-0 tile reads done
            #pragma unroll
            for (int k = 0; k < PREFK; ++k) {
                int i = t + 256 * k;
                if (i < NCHUNK) {
                    float4 v = pref[k];
                    int g = i * 4;
                    int y = g / W, x = g - y * W;
                    float* d = &tile[y * TS + x];
                    d[0] = v.x; d[1] = v.y; d[2] = v.z; d[3] = v.w;
                }
            }
            __syncthreads();
        }

        // row-prefix, chunked register scan: 20 pipelined reads, 20-add reg
        // chain, 20 writes.  bank(t, x0+k) = (5t + x0+k) & 31: distinct across
        // 32 lanes for fixed k -> conflict-free.
        if (t < H) {
            float* row = &tile[t * TS];
            float s = 0.f;
            for (int x0 = 0; x0 < W; x0 += SCHUNK) {
                float v[SCHUNK];
                #pragma unroll
                for (int k = 0; k < SCHUNK; ++k) v[k] = row[x0 + k];
                #pragma unroll
                for (int k = 0; k < SCHUNK; ++k) { s += v[k]; row[x0 + k] = s; }
            }
        }
        __syncthreads();

        // col-prefix, chunked register scan (lane-consecutive banks, free)
        if (t < W) {
            float s = 0.f;
            for (int y0 = 0; y0 < H; y0 += SCHUNK) {
                float v[SCHUNK];
                #pragma unroll
                for (int k = 0; k < SCHUNK; ++k) v[k] = tile[(y0 + k) * TS + t];
                #pragma unroll
                for (int k = 0; k < SCHUNK; ++k) { s += v[k]; tile[(y0 + k) * TS + t] = s; }
            }
        }
        __syncthreads();

        // ROI lookups.  Inclusive integral I[y][x] = sum_{y'<=y, x'<=x}.
        // rect rows [y0, y0+ys), cols [x0, x0+xs):
        // S = I[y1][x1] - I[y0-1][x1] - I[y1][x0-1] + I[y0-1][x0-1]
        for (int n = t; n < nrois; n += 256) {
            const int4 r  = ((const int4*)rois)[n];   // ymin,xmin,ymax,xmax
            const int ys  = (r.z - r.x) / KK;
            const int xs  = (r.w - r.y) / KK;
            const int y0  = r.x + j * ys;
            const int x0  = r.y + l * xs;
            const int y1  = y0 + ys - 1;              // <= 94 < 100
            const int x1  = x0 + xs - 1;

            float S = tile[y1 * TS + x1];
            if (x0 > 0)           S -= tile[y1 * TS + (x0 - 1)];
            if (y0 > 0)           S -= tile[(y0 - 1) * TS + x1];
            if (y0 > 0 && x0 > 0) S += tile[(y0 - 1) * TS + (x0 - 1)];

            const float w = 1.0f / (49.0f * (float)(ys * xs));
            atomicAdd(&acc[(size_t)n * C1 + c], S * w);
        }
        // pass-1 rewrite is barrier-guarded above, so pass-0 tile reads are safe
    }
}

// ---------------------------------------------------------------------------
// Stage 2: in-place softmax over the 21 channels of each ROI row.
// One thread per ROI; 21 consecutive floats per lane (L2-resident, 168 KB).
// ---------------------------------------------------------------------------
__global__ __launch_bounds__(64) void softmax_rows(float* __restrict__ outacc, int nrois)
{
    const int n = blockIdx.x * 64 + threadIdx.x;
    if (n >= nrois) return;
    float* row = outacc + (size_t)n * C1;

    float v[C1];
    float m = -INFINITY;
    #pragma unroll
    for (int c = 0; c < C1; ++c) { v[c] = row[c]; m = fmaxf(m, v[c]); }
    float s = 0.f;
    #pragma unroll
    for (int c = 0; c < C1; ++c) { v[c] = __expf(v[c] - m); s += v[c]; }
    const float rs = 1.0f / s;
    #pragma unroll
    for (int c = 0; c < C1; ++c) row[c] = v[c] * rs;
}

extern "C" void kernel_launch(void* const* d_in, const int* in_sizes, int n_in,
                              void* d_out, int out_size, void* d_ws, size_t ws_size,
                              hipStream_t stream)
{
    const float* cls  = (const float*)d_in[0];
    const int*   rois = (const int*)d_in[1];
    float*       out  = (float*)d_out;

    const int nrois = in_sizes[1] / 4;                         // 2000
    const size_t plane_elems = (size_t)NPLANES * H * W;        // 10.29 M
    const int B = (int)((size_t)in_sizes[0] / plane_elems);    // 4
    const size_t batch_off = (size_t)(B - 1) * plane_elems;

    const int ntot = nrois * C1;                               // 42000
    zero_out<<<(ntot + 255) / 256, 256, 0, stream>>>(out, ntot);

    const int nblocks = (NPLANES + 1) / 2;                     // 515
    plane_accum<<<nblocks, 256, 0, stream>>>(cls, batch_off, rois, nrois, out);

    softmax_rows<<<(nrois + 63) / 64, 64, 0, stream>>>(out, nrois);
}

// Round 2
// 215.104 us; speedup vs baseline: 1.4550x; 1.4550x over previous
//
#include <hip/hip_runtime.h>
#include <math.h>

#define KK      7
#define C1      21
#define NPLANES (KK * KK * C1)   // 1029
#define H       100
#define W       100
#define TS      101              // padded LDS row stride: bank stride 5 (coprime 32)
#define NCHUNK  ((H * W) / 4)    // 2500 float4 chunks per plane
#define PREFK   10               // ceil(2500 / 256)
#define SCHUNK  20               // register-scan chunk (100 = 5 * 20)

// ---------------------------------------------------------------------------
// Two-kernel structure (round-0, proven): partial[p][n] workspace + fused
// reduce/softmax.  Round-1 lesson: scatter atomicAdd into out[] write-throughs
// to HBM per-op (32B/atomic, 66MB) and cost ~100us -- never again.
// Round-1 keeper: chunked REGISTER scans for the integral image (20 pipelined
// ds_reads + 20-add reg chain + 20 writes per chunk) instead of 100 serial
// in-order LDS read->add->write round-trips per scan.
// ---------------------------------------------------------------------------
__global__ __launch_bounds__(256) void plane_partial(
    const float* __restrict__ src,   // full cls_conv_out
    size_t batch_off,                // offset of last batch element (elements)
    const int*  __restrict__ rois,   // [nrois][4] = ymin,xmin,ymax,xmax
    int nrois,
    float* __restrict__ partial)     // [NPLANES][nrois]
{
    const int t  = threadIdx.x;
    const int p0 = blockIdx.x * 2;
    const int p1 = p0 + 1;
    const bool has_p1 = (p1 < NPLANES);

    __shared__ float tile[H * TS];   // 40400 B

    // ---- stage plane 0 (float4 global -> scalar padded LDS) ----
    {
        const float4* p4 = (const float4*)(src + batch_off + (size_t)p0 * (H * W));
        #pragma unroll
        for (int k = 0; k < PREFK; ++k) {
            int i = t + 256 * k;
            if (i < NCHUNK) {
                float4 v = p4[i];
                int g = i * 4;
                int y = g / W, x = g - y * W;        // rows don't split (100%4==0)
                float* d = &tile[y * TS + x];
                d[0] = v.x; d[1] = v.y; d[2] = v.z; d[3] = v.w;
            }
        }
    }
    __syncthreads();

    // ---- issue prefetch of plane 1 into registers (loads stay in flight) ----
    float4 pref[PREFK];
    if (has_p1) {
        const float4* p4 = (const float4*)(src + batch_off + (size_t)p1 * (H * W));
        #pragma unroll
        for (int k = 0; k < PREFK; ++k) {
            int i = t + 256 * k;
            if (i < NCHUNK) pref[k] = p4[i];
        }
    }

    for (int pass = 0; pass < 2; ++pass) {
        const int p = p0 + pass;
        if (p >= NPLANES) break;
        const int jl = p / C1;
        const int l  = jl % KK;
        const int j  = jl / KK;

        if (pass == 1) {
            // overwrite tile with the prefetched plane
            __syncthreads();          // all pass-0 tile reads done
            #pragma unroll
            for (int k = 0; k < PREFK; ++k) {
                int i = t + 256 * k;
                if (i < NCHUNK) {
                    float4 v = pref[k];
                    int g = i * 4;
                    int y = g / W, x = g - y * W;
                    float* d = &tile[y * TS + x];
                    d[0] = v.x; d[1] = v.y; d[2] = v.z; d[3] = v.w;
                }
            }
            __syncthreads();
        }

        // row-prefix, chunked register scan: 20 pipelined reads, 20-add reg
        // chain, 20 writes.  bank(t, x0+k) = (5t + x0+k) & 31: distinct across
        // 32 lanes for fixed k -> conflict-free.
        if (t < H) {
            float* row = &tile[t * TS];
            float s = 0.f;
            for (int x0 = 0; x0 < W; x0 += SCHUNK) {
                float v[SCHUNK];
                #pragma unroll
                for (int k = 0; k < SCHUNK; ++k) v[k] = row[x0 + k];
                #pragma unroll
                for (int k = 0; k < SCHUNK; ++k) { s += v[k]; row[x0 + k] = s; }
            }
        }
        __syncthreads();

        // col-prefix, chunked register scan (lane-consecutive banks, free)
        if (t < W) {
            float s = 0.f;
            for (int y0 = 0; y0 < H; y0 += SCHUNK) {
                float v[SCHUNK];
                #pragma unroll
                for (int k = 0; k < SCHUNK; ++k) v[k] = tile[(y0 + k) * TS + t];
                #pragma unroll
                for (int k = 0; k < SCHUNK; ++k) { s += v[k]; tile[(y0 + k) * TS + t] = s; }
            }
        }
        __syncthreads();

        // ROI lookups.  Inclusive integral I[y][x] = sum_{y'<=y, x'<=x}.
        // rect rows [y0, y0+ys), cols [x0, x0+xs):
        // S = I[y1][x1] - I[y0-1][x1] - I[y1][x0-1] + I[y0-1][x0-1]
        float* prow = partial + (size_t)p * nrois;
        for (int n = t; n < nrois; n += 256) {
            const int4 r  = ((const int4*)rois)[n];   // ymin,xmin,ymax,xmax
            const int ys  = (r.z - r.x) / KK;
            const int xs  = (r.w - r.y) / KK;
            const int y0  = r.x + j * ys;
            const int x0  = r.y + l * xs;
            const int y1  = y0 + ys - 1;              // <= 94 < 100
            const int x1  = x0 + xs - 1;

            float S = tile[y1 * TS + x1];
            if (x0 > 0)           S -= tile[y1 * TS + (x0 - 1)];
            if (y0 > 0)           S -= tile[(y0 - 1) * TS + x1];
            if (y0 > 0 && x0 > 0) S += tile[(y0 - 1) * TS + (x0 - 1)];

            prow[n] = S;                              // coalesced 4B store
        }
    }
}

// ---------------------------------------------------------------------------
// Stage 2 (fused reduce + softmax): block handles RB=16 ROIs.
// Thread (dn = t%16, cg = t/16) sums channels c = cg, cg+16 over 49 planes
// with 64B-coalesced loads (16 consecutive n per channel-row).  LDS ch[16][21],
// then lanes 0..15 do the per-ROI scale + softmax + store.
// ---------------------------------------------------------------------------
#define RB 16

__global__ __launch_bounds__(256) void reduce_softmax(
    const float* __restrict__ partial,   // [NPLANES][nrois]
    const int*   __restrict__ rois,
    int nrois,
    float*       __restrict__ out)
{
    const int dn = threadIdx.x & (RB - 1);
    const int cg = threadIdx.x / RB;     // 0..15
    const int n  = blockIdx.x * RB + dn;

    __shared__ float ch[RB][C1];

    if (n < nrois) {
        for (int c = cg; c < C1; c += 16) {
            float s = 0.f;
            const float* pc = partial + (size_t)c * nrois + n;
            #pragma unroll
            for (int jl = 0; jl < KK * KK; ++jl) {
                s += pc[(size_t)jl * C1 * nrois];
            }
            ch[dn][c] = s;
        }
    }
    __syncthreads();

    if (threadIdx.x < RB) {
        const int n2 = blockIdx.x * RB + threadIdx.x;
        if (n2 < nrois) {
            const int4 r  = ((const int4*)rois)[n2];
            const int ys  = (r.z - r.x) / KK;
            const int xs  = (r.w - r.y) / KK;
            const float inv = 1.0f / (49.0f * (float)(ys * xs));

            float v[C1];
            float m = -INFINITY;
            #pragma unroll
            for (int c = 0; c < C1; ++c) {
                v[c] = ch[threadIdx.x][c] * inv;
                m = fmaxf(m, v[c]);
            }
            float s = 0.f;
            #pragma unroll
            for (int c = 0; c < C1; ++c) { v[c] = __expf(v[c] - m); s += v[c]; }
            const float rs = 1.0f / s;
            #pragma unroll
            for (int c = 0; c < C1; ++c) out[(size_t)n2 * C1 + c] = v[c] * rs;
        }
    }
}

// ---------------------------------------------------------------------------
// Fallback (ws too small): direct rectangle summation from global.
// ---------------------------------------------------------------------------
__global__ __launch_bounds__(256) void roi_pool_direct(
    const float* __restrict__ src,
    size_t batch_off,
    const int*   __restrict__ rois,
    float*       __restrict__ out)
{
    const int n = blockIdx.x;
    const int t = threadIdx.x;

    __shared__ float chsum[C1];
    if (t < C1) chsum[t] = 0.f;
    __syncthreads();

    const int ymin = rois[4 * n + 0];
    const int xmin = rois[4 * n + 1];
    const int ymax = rois[4 * n + 2];
    const int xmax = rois[4 * n + 3];
    const int ys = (ymax - ymin) / KK;
    const int xs = (xmax - xmin) / KK;

    const float* base = src + batch_off;

    for (int idx = t; idx < NPLANES; idx += blockDim.x) {
        const int c  = idx % C1;
        const int jl = idx / C1;
        const int l  = jl % KK;
        const int j  = jl / KK;
        const int y0 = ymin + j * ys;
        const int x0 = xmin + l * xs;
        const float* plane = base + (size_t)idx * (H * W);
        float s = 0.f;
        for (int y = y0; y < y0 + ys; ++y) {
            const float* row = plane + (size_t)y * W + x0;
            for (int x = 0; x < xs; ++x) s += row[x];
        }
        atomicAdd(&chsum[c], s);
    }
    __syncthreads();

    if (t == 0) {
        const float inv = 1.0f / (49.0f * (float)(ys * xs));
        float m = -INFINITY;
        float v[C1];
        for (int c = 0; c < C1; ++c) { v[c] = chsum[c] * inv; m = fmaxf(m, v[c]); }
        float s = 0.f;
        for (int c = 0; c < C1; ++c) { v[c] = expf(v[c] - m); s += v[c]; }
        const float rs = 1.0f / s;
        for (int c = 0; c < C1; ++c) out[(size_t)n * C1 + c] = v[c] * rs;
    }
}

extern "C" void kernel_launch(void* const* d_in, const int* in_sizes, int n_in,
                              void* d_out, int out_size, void* d_ws, size_t ws_size,
                              hipStream_t stream)
{
    const float* cls  = (const float*)d_in[0];
    const int*   rois = (const int*)d_in[1];
    float*       out  = (float*)d_out;

    const int nrois = in_sizes[1] / 4;                         // 2000
    const size_t plane_elems = (size_t)NPLANES * H * W;        // 10.29 M
    const int B = (int)((size_t)in_sizes[0] / plane_elems);    // 4
    const size_t batch_off = (size_t)(B - 1) * plane_elems;

    const size_t need = (size_t)NPLANES * nrois * sizeof(float);  // ~8.2 MB
    if (ws_size >= need) {
        float* partial = (float*)d_ws;
        const int nblocks = (NPLANES + 1) / 2;                 // 515
        plane_partial<<<nblocks, 256, 0, stream>>>(cls, batch_off, rois, nrois, partial);
        reduce_softmax<<<(nrois + RB - 1) / RB, 256, 0, stream>>>(partial, rois, nrois, out);
    } else {
        roi_pool_direct<<<nrois, 256, 0, stream>>>(cls, batch_off, rois, out);
    }
}